// Round 3
// baseline (659.678 us; speedup 1.0000x reference)
//
#include <hip/hip_runtime.h>
#include <math.h>

#define NB 8192
#define DIN 1024
#define DOUT 768
#define NE 16

#define RB 32            // rows per block (gating kernel)
#define KT 64            // K-tile
#define NT (DIN / KT)    // 16 tiles
#define LDW 68           // LDS row stride (floats) for x/w tiles: 16B-aligned rows, good b128 banking
#define LDG 129          // LDS row stride for G exchange: conflict-free column access
#define NSEL 60
#define NCOL 124

#define SOFT_OFF 6291456
#define HARD_OFF 6291472
#define SC_OFF   6291488
#define REG_OFF  6422560

__device__ __forceinline__ float smooth_step_f(float t) {
  float p = -2.0f * t * t * t + 1.5f * t + 0.5f;
  p = (t <= -0.5f) ? 0.0f : p;
  p = (t >= 0.5f) ? 1.0f : p;
  return p;
}

// ---------------- K12: fused gating GEMM + tree + softmax + stats ----------------
// grid 256 blocks x 256 threads; block owns rows [b0, b0+32)
__global__ __launch_bounds__(256) void k12_gate(
    const float* __restrict__ x, const float* __restrict__ sel_w,
    const float* __restrict__ leaf_w, const float* __restrict__ leaf_b,
    float* __restrict__ wnorm, float* __restrict__ out)
{
  __shared__ float xs[RB * LDW];     //  8.7 KB
  __shared__ float wsm[128 * LDW];   // 34.8 KB
  __shared__ float gsm[RB * LDG];    // 16.5 KB
  const int t  = threadIdx.x;
  const int b0 = blockIdx.x * RB;
  const int tr = t >> 5;   // 0..7  -> rows tr+8i
  const int tc = t & 31;   // 0..31 -> cols tc+32j

  float acc[4][4];
#pragma unroll
  for (int i = 0; i < 4; ++i)
#pragma unroll
    for (int j = 0; j < 4; ++j) acc[i][j] = 0.0f;

  // staging float4 assignments
  int xr[2], xk[2];          // x: 512 float4 per tile
#pragma unroll
  for (int m = 0; m < 2; ++m) { int f = t + 256 * m; xr[m] = f >> 4; xk[m] = (f & 15) * 4; }
  int wc[8], wk[8];          // w: 2048 float4 per tile
#pragma unroll
  for (int m = 0; m < 8; ++m) { int f = t + 256 * m; wc[m] = f >> 4; wk[m] = (f & 15) * 4; }

  float4 px[2], pw[8];
  // load tile 0
#pragma unroll
  for (int m = 0; m < 2; ++m)
    px[m] = *(const float4*)(x + (size_t)(b0 + xr[m]) * DIN + xk[m]);
#pragma unroll
  for (int m = 0; m < 8; ++m) {
    int c = wc[m];
    if (c < NSEL)      pw[m] = *(const float4*)(sel_w + (size_t)c * DIN + wk[m]);
    else if (c < NCOL) pw[m] = *(const float4*)(leaf_w + (size_t)(c - NSEL) * DIN + wk[m]);
    else               pw[m] = make_float4(0.f, 0.f, 0.f, 0.f);
  }

  for (int kt = 0; kt < NT; ++kt) {
    // commit staged regs
#pragma unroll
    for (int m = 0; m < 2; ++m) *(float4*)(&xs[xr[m] * LDW + xk[m]]) = px[m];
#pragma unroll
    for (int m = 0; m < 8; ++m) *(float4*)(&wsm[wc[m] * LDW + wk[m]]) = pw[m];
    __syncthreads();
    // prefetch next tile
    if (kt + 1 < NT) {
      int kb = (kt + 1) * KT;
#pragma unroll
      for (int m = 0; m < 2; ++m)
        px[m] = *(const float4*)(x + (size_t)(b0 + xr[m]) * DIN + kb + xk[m]);
#pragma unroll
      for (int m = 0; m < 8; ++m) {
        int c = wc[m];
        if (c < NSEL)      pw[m] = *(const float4*)(sel_w + (size_t)c * DIN + kb + wk[m]);
        else if (c < NCOL) pw[m] = *(const float4*)(leaf_w + (size_t)(c - NSEL) * DIN + kb + wk[m]);
        else               pw[m] = make_float4(0.f, 0.f, 0.f, 0.f);
      }
    }
#pragma unroll 8
    for (int kk = 0; kk < KT; kk += 4) {
      float4 xv[4], wv[4];
#pragma unroll
      for (int i = 0; i < 4; ++i) xv[i] = *(const float4*)(&xs[(tr + 8 * i) * LDW + kk]);
#pragma unroll
      for (int j = 0; j < 4; ++j) wv[j] = *(const float4*)(&wsm[(tc + 32 * j) * LDW + kk]);
#pragma unroll
      for (int i = 0; i < 4; ++i)
#pragma unroll
        for (int j = 0; j < 4; ++j) {
          acc[i][j] = fmaf(xv[i].x, wv[j].x, acc[i][j]);
          acc[i][j] = fmaf(xv[i].y, wv[j].y, acc[i][j]);
          acc[i][j] = fmaf(xv[i].z, wv[j].z, acc[i][j]);
          acc[i][j] = fmaf(xv[i].w, wv[j].w, acc[i][j]);
        }
    }
    __syncthreads();
  }

  // exchange G through LDS
#pragma unroll
  for (int i = 0; i < 4; ++i)
#pragma unroll
    for (int j = 0; j < 4; ++j)
      gsm[(tr + 8 * i) * LDG + tc + 32 * j] = acc[i][j];
  __syncthreads();

  // ---- phase 2: tree + softmax + stats, one thread per row (threads 0..31, all wave 0) ----
  if (t < RB) {
    const int b = b0 + t;
    const float* gr = &gsm[t * LDG];

    float s_arr[64];
    float rsum = 0.0f;
#pragma unroll
    for (int k = 0; k < 4; ++k) {
      float gt[15];
#pragma unroll
      for (int n = 0; n < 15; ++n) gt[n] = smooth_step_f(gr[n * 4 + k]);
#pragma unroll
      for (int l = 0; l < 16; ++l) {
        float g0 = gt[0];
        float g1 = gt[1 + (l >> 3)];
        float g2 = gt[3 + (l >> 2)];
        float g3 = gt[7 + (l >> 1)];
        float f0 = ((l >> 3) & 1) ? (1.0f - g0) : g0;
        float f1 = ((l >> 2) & 1) ? (1.0f - g1) : g1;
        float f2 = ((l >> 1) & 1) ? (1.0f - g2) : g2;
        float f3 = (l & 1)        ? (1.0f - g3) : g3;
        float p = ((f0 * f1) * f2) * f3;
        float pc = fmaxf(p, 1e-6f);
        float lg = logf(pc + 1e-6f);
        rsum += -(pc + 1e-6f) * lg;
        float av = gr[NSEL + l * 4 + k] + leaf_b[l * 4 + k];
        s_arr[l * 4 + k] = (p < 1e-5f) ? -INFINITY : (av + lg);
      }
    }

    float m = s_arr[0];
#pragma unroll
    for (int i = 1; i < 64; ++i) m = fmaxf(m, s_arr[i]);

    float we[16];
#pragma unroll
    for (int e = 0; e < 16; ++e) we[e] = 0.0f;
    float sum = 0.0f;
#pragma unroll
    for (int e = 0; e < 16; ++e)
#pragma unroll
      for (int k = 0; k < 4; ++k) {
        float wv = expf(s_arr[e * 4 + k] - m);
        sum += wv;
        we[e] += wv;
      }
    float inv = 1.0f / sum;

    float softp[16], hardp[16];
#pragma unroll
    for (int e = 0; e < 16; ++e) {
      float wn = we[e] * inv;
      softp[e] = wn;
      float sc = (wn < 1e-5f) ? 1.0f : 0.0f;
      hardp[e] = 1.0f - sc;
      wnorm[(size_t)b * NE + e] = wn;
      out[SC_OFF + (size_t)b * NE + e] = sc;
    }

    // half-wave reduce over lanes 0..31 (lane 0's dependency cone stays in active lanes)
#pragma unroll
    for (int e = 0; e < 16; ++e) {
      float v = softp[e];
      v += __shfl_down(v, 16, 64); v += __shfl_down(v, 8, 64);
      v += __shfl_down(v, 4, 64);  v += __shfl_down(v, 2, 64); v += __shfl_down(v, 1, 64);
      float hv = hardp[e];
      hv += __shfl_down(hv, 16, 64); hv += __shfl_down(hv, 8, 64);
      hv += __shfl_down(hv, 4, 64);  hv += __shfl_down(hv, 2, 64); hv += __shfl_down(hv, 1, 64);
      if (t == 0) {
        atomicAdd(&out[SOFT_OFF + e], v * (1.0f / (float)NB));
        atomicAdd(&out[HARD_OFF + e], hv * (1.0f / (float)NB));
      }
    }
    {
      float v = rsum;
      v += __shfl_down(v, 16, 64); v += __shfl_down(v, 8, 64);
      v += __shfl_down(v, 4, 64);  v += __shfl_down(v, 2, 64); v += __shfl_down(v, 1, 64);
      if (t == 0) atomicAdd(&out[REG_OFF], v * (0.01f / (float)NB));
    }
  }
}

// ---------------- K3: y_agg[b,d] = sum_e h[b,d,e] * w_norm[b,e] ----------------
__global__ __launch_bounds__(256) void k3_yagg(
    const float* __restrict__ h, const float* __restrict__ wnorm,
    float* __restrict__ out)
{
  const int b = blockIdx.x;
  __shared__ float wl[NE];
  if (threadIdx.x < NE) wl[threadIdx.x] = wnorm[(size_t)b * NE + threadIdx.x];
  __syncthreads();
  float w[NE];
#pragma unroll
  for (int e = 0; e < NE; ++e) w[e] = wl[e];

#pragma unroll
  for (int mm = 0; mm < 3; ++mm) {
    int d = threadIdx.x + 256 * mm;
    const float4* hp = (const float4*)(h + ((size_t)b * DOUT + d) * NE);
    float4 h0 = hp[0], h1 = hp[1], h2 = hp[2], h3 = hp[3];
    float acc;
    acc  = h0.x * w[0]  + h0.y * w[1]  + h0.z * w[2]  + h0.w * w[3];
    acc += h1.x * w[4]  + h1.y * w[5]  + h1.z * w[6]  + h1.w * w[7];
    acc += h2.x * w[8]  + h2.y * w[9]  + h2.z * w[10] + h2.w * w[11];
    acc += h3.x * w[12] + h3.y * w[13] + h3.z * w[14] + h3.w * w[15];
    out[(size_t)b * DOUT + d] = acc;
  }
}

extern "C" void kernel_launch(void* const* d_in, const int* in_sizes, int n_in,
                              void* d_out, int out_size, void* d_ws, size_t ws_size,
                              hipStream_t stream)
{
  const float* h      = (const float*)d_in[0];
  const float* x      = (const float*)d_in[1];
  const float* sel_w  = (const float*)d_in[2];
  const float* leaf_w = (const float*)d_in[3];
  const float* leaf_b = (const float*)d_in[4];
  float* out = (float*)d_out;

  float* wnorm = (float*)d_ws;   // [8192][16]

  // zero the atomically-accumulated outputs
  hipMemsetAsync(out + SOFT_OFF, 0, 32 * sizeof(float), stream);  // soft+hard contiguous
  hipMemsetAsync(out + REG_OFF, 0, sizeof(float), stream);

  k12_gate<<<NB / RB, 256, 0, stream>>>(x, sel_w, leaf_w, leaf_b, wnorm, out);
  k3_yagg<<<NB, 256, 0, stream>>>(h, wnorm, out);
}